// Round 9
// baseline (216.048 us; speedup 1.0000x reference)
//
#include <hip/hip_runtime.h>
#include <math.h>

#define TT 2
#define CH 128
#define HH 96
#define WW 96
#define HWS 9216            // H*W
#define QTOT 18432          // T*H*W
#define QC (QTOT*CH)
#define HD 32
#define KTOP 16
#define SCALE 0.17677669529663687f  // 32^-0.5

#define SEG 16              // queries per attn block (one row segment)
#define PR 8                // patch rows
#define PC 23               // patch cols
#define PSTRIDE 36          // floats per patch pixel in LDS

typedef __attribute__((ext_vector_type(8))) short short8;
typedef __attribute__((ext_vector_type(4))) float floatx4;

__device__ __forceinline__ unsigned short f2bf(float f) {
    union { float f; unsigned u; } x; x.f = f;
    unsigned r = x.u + 0x7fffu + ((x.u >> 16) & 1u);
    return (unsigned short)(r >> 16);
}
__device__ __forceinline__ float bf2f(unsigned short h) {
    return __uint_as_float(((unsigned)h) << 16);
}

__device__ __forceinline__ int refl(int x, int n) {
    x = x < 0 ? -x : x;
    return x >= n ? 2 * (n - 1) - x : x;
}

// ------ FUSED depthwise 3x3 + bf16 convert: vid -> qk_hi/lo, v_bf, all [p][c] ---------
__global__ __launch_bounds__(256) void dwcvt_kernel(
    const float* __restrict__ x,
    const float* __restrict__ wq, const float* __restrict__ wk, const float* __restrict__ wv,
    unsigned short* __restrict__ qk_hi,   // [2][p][c]
    unsigned short* __restrict__ qk_lo,   // [2][p][c]
    unsigned short* __restrict__ v_bf)    // [p][c]
{
    int t = threadIdx.x;
    int pl = t & 63;
    int cg = __builtin_amdgcn_readfirstlane(t >> 6);   // wave-uniform channel group
    int p  = blockIdx.x * 64 + pl;
    int c0 = blockIdx.y * 32 + cg * 8;
    int hw = p % HWS;
    int tt = p / HWS;
    int i = hw / WW, j = hw % WW;

    unsigned qh[4], ql[4], kh[4], kl[4], vh4[4];
#pragma unroll
    for (int ic = 0; ic < 8; ic += 2) {
        float sv[3][2];
#pragma unroll
        for (int u = 0; u < 2; u++) {
            int c = c0 + ic + u;
            const float* xp = x + (size_t)(tt * CH + c) * HWS;
            float w0[9], w1[9], w2[9];
#pragma unroll
            for (int r = 0; r < 9; r++) {
                w0[r] = wq[c * 9 + r]; w1[r] = wk[c * 9 + r]; w2[r] = wv[c * 9 + r];
            }
            float s0 = 0.f, s1 = 0.f, s2 = 0.f;
#pragma unroll
            for (int r = 0; r < 3; r++) {
                int ii = i + r - 1;
                if (ii < 0 || ii >= HH) continue;
#pragma unroll
                for (int ss = 0; ss < 3; ss++) {
                    int jj = j + ss - 1;
                    if (jj < 0 || jj >= WW) continue;
                    float xv = xp[ii * WW + jj];
                    s0 += xv * w0[r * 3 + ss];
                    s1 += xv * w1[r * 3 + ss];
                    s2 += xv * w2[r * 3 + ss];
                }
            }
            sv[0][u] = s0; sv[1][u] = s1; sv[2][u] = s2;
        }
        int w = ic >> 1;
        unsigned short h0 = f2bf(sv[0][0]), h1 = f2bf(sv[0][1]);
        qh[w] = h0 | ((unsigned)h1 << 16);
        ql[w] = f2bf(sv[0][0] - bf2f(h0)) | ((unsigned)f2bf(sv[0][1] - bf2f(h1)) << 16);
        h0 = f2bf(sv[1][0]); h1 = f2bf(sv[1][1]);
        kh[w] = h0 | ((unsigned)h1 << 16);
        kl[w] = f2bf(sv[1][0] - bf2f(h0)) | ((unsigned)f2bf(sv[1][1] - bf2f(h1)) << 16);
        vh4[w] = f2bf(sv[2][0]) | ((unsigned)f2bf(sv[2][1]) << 16);
    }
    size_t off = (size_t)p * CH + c0;
    uint4 pk;
    pk.x = qh[0]; pk.y = qh[1]; pk.z = qh[2]; pk.w = qh[3];
    *(uint4*)(qk_hi + off) = pk;
    pk.x = ql[0]; pk.y = ql[1]; pk.z = ql[2]; pk.w = ql[3];
    *(uint4*)(qk_lo + off) = pk;
    pk.x = kh[0]; pk.y = kh[1]; pk.z = kh[2]; pk.w = kh[3];
    *(uint4*)(qk_hi + (size_t)QC + off) = pk;
    pk.x = kl[0]; pk.y = kl[1]; pk.z = kl[2]; pk.w = kl[3];
    *(uint4*)(qk_lo + (size_t)QC + off) = pk;
    pk.x = vh4[0]; pk.y = vh4[1]; pk.z = vh4[2]; pk.w = vh4[3];
    *(uint4*)(v_bf + off) = pk;
}

// ------ ONE dispatch: y=0/1 qk bf16x3 GEMM, y=2 v GEMM -> per-head bf16, y=3 wprep -----
__global__ __launch_bounds__(256) void qkv_mfma(
    const unsigned short* __restrict__ Ahi,   // [2][p][c]
    const unsigned short* __restrict__ Alo,
    const unsigned short* __restrict__ Avb,   // v_bf [p][c]
    const float* __restrict__ wq_pw, const float* __restrict__ wk_pw,
    const float* __restrict__ wv_pw, const float* __restrict__ proj_w,
    const float* __restrict__ bq, const float* __restrict__ bk, const float* __restrict__ bv,
    float* __restrict__ qkf,                  // q -> qkf[0], k -> qkf[1] ([p][c] fp32)
    unsigned short* __restrict__ vh,          // [4][QTOT][32] bf16
    unsigned short* __restrict__ wp_bf)       // proj_w bf16 [o][c]
{
    __shared__ unsigned short WhS[128 * 136];
    __shared__ unsigned short WlS[128 * 136];
    int sel = blockIdx.y;
    int t = threadIdx.x;

    if (sel == 3) {                    // proj weight prep (tiny)
        if (blockIdx.x < 16) {
            int idx = blockIdx.x * 256 + t;
            float4 w4 = *(const float4*)(proj_w + idx * 4);
            uint2 pk;
            pk.x = f2bf(w4.x) | ((unsigned)f2bf(w4.y) << 16);
            pk.y = f2bf(w4.z) | ((unsigned)f2bf(w4.w) << 16);
            *(uint2*)(wp_bf + idx * 4) = pk;
        }
        return;
    }

    int wv = t >> 6, lane = t & 63;
    int m = lane & 15, quad = lane >> 4;
    int p0 = blockIdx.x * 64;
    int o0 = wv * 32;

    if (sel == 2) {                    // v GEMM (single-pass bf16)
#pragma unroll
        for (int r = 0; r < 16; r++) {
            int lin = r * 256 + t;
            int o = lin >> 5, cq = lin & 31;
            float4 w4 = *(const float4*)(wv_pw + o * CH + cq * 4);
            uint2 pk;
            pk.x = f2bf(w4.x) | ((unsigned)f2bf(w4.y) << 16);
            pk.y = f2bf(w4.z) | ((unsigned)f2bf(w4.w) << 16);
            *(uint2*)(&WhS[o * 136 + cq * 4]) = pk;
        }
        __syncthreads();
        float bb[2];
#pragma unroll
        for (int ot = 0; ot < 2; ot++) bb[ot] = bv[o0 + ot * 16 + m];
        floatx4 acc[4][2];
#pragma unroll
        for (int i = 0; i < 4; i++)
#pragma unroll
            for (int j = 0; j < 2; j++) acc[i][j] = (floatx4){0.f, 0.f, 0.f, 0.f};
#pragma unroll
        for (int kc = 0; kc < 4; kc++) {
            short8 a[4], b[2];
#pragma unroll
            for (int pt = 0; pt < 4; pt++)
                a[pt] = *(const short8*)(Avb + (size_t)(p0 + pt * 16 + m) * CH + kc * 32 + quad * 8);
#pragma unroll
            for (int ot = 0; ot < 2; ot++)
                b[ot] = *(const short8*)(&WhS[(o0 + ot * 16 + m) * 136 + kc * 32 + quad * 8]);
#pragma unroll
            for (int pt = 0; pt < 4; pt++)
#pragma unroll
                for (int ot = 0; ot < 2; ot++)
                    acc[pt][ot] = __builtin_amdgcn_mfma_f32_16x16x32_bf16(a[pt], b[ot], acc[pt][ot], 0, 0, 0);
        }
        // epilogue: h = wv (c = wv*32 + ot*16 + m), per-head gather layout
        unsigned short* vhh = vh + (size_t)wv * QTOT * 32;
#pragma unroll
        for (int pt = 0; pt < 4; pt++)
#pragma unroll
            for (int ot = 0; ot < 2; ot++)
#pragma unroll
                for (int reg = 0; reg < 4; reg++) {
                    int p = p0 + pt * 16 + quad * 4 + reg;
                    vhh[(size_t)p * 32 + ot * 16 + m] = f2bf(acc[pt][ot][reg] + bb[ot]);
                }
        return;
    }

    // sel 0/1: q,k via bf16x3 split (fp32-emulating)
    const float* W = sel ? wk_pw : wq_pw;
    const float* bias = sel ? bk : bq;
    float scale = sel ? 1.f : SCALE;
    const unsigned short* ah = Ahi + (size_t)sel * QC;
    const unsigned short* al = Alo + (size_t)sel * QC;
    float* O = qkf + (size_t)sel * QC;

#pragma unroll
    for (int r = 0; r < 16; r++) {
        int lin = r * 256 + t;
        int o = lin >> 5, cq = lin & 31;
        float4 w4 = *(const float4*)(W + o * CH + cq * 4);
        unsigned short hx = f2bf(w4.x), hy = f2bf(w4.y), hz = f2bf(w4.z), hw = f2bf(w4.w);
        unsigned short lx = f2bf(w4.x - bf2f(hx)), ly = f2bf(w4.y - bf2f(hy));
        unsigned short lz = f2bf(w4.z - bf2f(hz)), lw = f2bf(w4.w - bf2f(hw));
        uint2 pk;
        pk.x = hx | ((unsigned)hy << 16); pk.y = hz | ((unsigned)hw << 16);
        *(uint2*)(&WhS[o * 136 + cq * 4]) = pk;
        pk.x = lx | ((unsigned)ly << 16); pk.y = lz | ((unsigned)lw << 16);
        *(uint2*)(&WlS[o * 136 + cq * 4]) = pk;
    }
    __syncthreads();
    float bb[2];
#pragma unroll
    for (int ot = 0; ot < 2; ot++) bb[ot] = bias[o0 + ot * 16 + m];
    floatx4 acc[4][2];
#pragma unroll
    for (int i = 0; i < 4; i++)
#pragma unroll
        for (int j = 0; j < 2; j++) acc[i][j] = (floatx4){0.f, 0.f, 0.f, 0.f};
#pragma unroll
    for (int kc = 0; kc < 4; kc++) {
        short8 avh[4], avl[4], bh[2], bl[2];
#pragma unroll
        for (int pt = 0; pt < 4; pt++) {
            size_t base = (size_t)(p0 + pt * 16 + m) * CH + kc * 32 + quad * 8;
            avh[pt] = *(const short8*)(ah + base);
            avl[pt] = *(const short8*)(al + base);
        }
#pragma unroll
        for (int ot = 0; ot < 2; ot++) {
            int lidx = (o0 + ot * 16 + m) * 136 + kc * 32 + quad * 8;
            bh[ot] = *(const short8*)(&WhS[lidx]);
            bl[ot] = *(const short8*)(&WlS[lidx]);
        }
#pragma unroll
        for (int pt = 0; pt < 4; pt++)
#pragma unroll
            for (int ot = 0; ot < 2; ot++) {
                acc[pt][ot] = __builtin_amdgcn_mfma_f32_16x16x32_bf16(avh[pt], bh[ot], acc[pt][ot], 0, 0, 0);
                acc[pt][ot] = __builtin_amdgcn_mfma_f32_16x16x32_bf16(avh[pt], bl[ot], acc[pt][ot], 0, 0, 0);
                acc[pt][ot] = __builtin_amdgcn_mfma_f32_16x16x32_bf16(avl[pt], bh[ot], acc[pt][ot], 0, 0, 0);
            }
    }
#pragma unroll
    for (int pt = 0; pt < 4; pt++)
#pragma unroll
        for (int ot = 0; ot < 2; ot++)
#pragma unroll
            for (int reg = 0; reg < 4; reg++) {
                int p = p0 + pt * 16 + quad * 4 + reg;
                O[(size_t)p * CH + o0 + ot * 16 + m] = (acc[pt][ot][reg] + bb[ot]) * scale;
            }
}

// ------ FUSED attention + proj: block = 16-px segment, loops 4 heads, proj epilogue -----
__global__ __launch_bounds__(256) void attnproj_kernel(
    const float* __restrict__ q,    // qkf[0] [p][128] fp32
    const float* __restrict__ k,    // qkf[1]
    const unsigned short* __restrict__ vh,   // [4][QTOT][32] bf16
    const unsigned short* __restrict__ wp,   // proj_w bf16 [o][c]
    const float* __restrict__ pb,
    float* __restrict__ out)        // NCHW fp32
{
    __shared__ float kp[PR * PC * PSTRIDE];       // 26.5 KB
    __shared__ unsigned short att_s[16 * 136];    // 4.25 KB
    int n = blockIdx.x;
    int seg = (n & 7) * 144 + (n >> 3);           // XCD-band swizzle
    int qj0 = (seg % (WW / SEG)) * SEG;
    int qi = (seg / (WW / SEG)) % HH;
    int tt = seg / ((WW / SEG) * HH);
    int t = threadIdx.x;
    int wv = t >> 6, lane = t & 63;
    int ci = lane >> 3, cjo = lane & 7;
    int di = ci - 4, dj = cjo - 4;
    int rowoff = tt * HWS + refl(qi + di, HH) * WW;
    const int d = lane & (HD - 1);
    const unsigned long long below = (1ull << lane) - 1ull;

    for (int h = 0; h < 4; h++) {
        if (h) __syncthreads();
        // stage reflected k patch for head h: coalesced
#pragma unroll
        for (int r = 0; r < 6; r++) {
            int f = r * 256 + t;
            if (f < PR * PC * 8) {
                int pix = f >> 3, d4 = f & 7;
                int pci = pix / PC, pcj = pix - pci * PC;
                int gi = refl(qi + pci - 4, HH);
                int gj = refl(qj0 + pcj - 4, WW);
                int gp = tt * HWS + gi * WW + gj;
                *(float4*)(&kp[pix * PSTRIDE + d4 * 4]) =
                    *(const float4*)(k + (size_t)gp * CH + h * HD + d4 * 4);
            }
        }
        __syncthreads();

        const unsigned short* vhh = vh + (size_t)h * QTOT * 32;
        for (int ql = wv * 4; ql < wv * 4 + 4; ql++) {
            int qj = qj0 + ql;
            int p = tt * HWS + qi * WW + qj;
            const float* qp = q + (size_t)p * CH + h * HD;
            const float* kr = &kp[(ci * PC + ql + cjo) * PSTRIDE];
            float dist = 0.f;
#pragma unroll
            for (int dd = 0; dd < 8; dd++) {
                float4 qv = *(const float4*)(qp + dd * 4);
                float4 kv = *(const float4*)(kr + dd * 4);
                dist += qv.x * kv.x + qv.y * kv.y + qv.z * kv.z + qv.w * kv.w;
            }
            int cpix = rowoff + refl(qj + dj, WW);

            // order-preserving uint key (desc select)
            unsigned u = __float_as_uint(dist);
            unsigned key = (u & 0x80000000u) ? ~u : (u | 0x80000000u);

            // fixed-32 branch-free radix select of the 16th-largest key
            unsigned prefix = 0u;
            int need = KTOP;
#pragma unroll
            for (int bit = 31; bit >= 0; --bit) {
                unsigned hi = (prefix >> bit) | 1u;
                unsigned long long b = __ballot((key >> bit) == hi);
                int cnt = __popcll(b);
                bool take = cnt >= need;
                prefix = take ? (prefix | (1u << bit)) : prefix;
                need = take ? need : need - cnt;
            }
            bool isEq = (key == prefix);
            unsigned long long eqm = __ballot(isEq);
            int rk = __popcll(eqm & below);
            bool selb = (key > prefix) || (isEq && rk < need);
            unsigned long long selm = __ballot(selb);

            float e = selb ? __expf(dist) : 0.f;

            float acc = 0.f, denom = 0.f;
            unsigned long long m0 = selm;
#pragma unroll
            for (int r = 0; r < KTOP; r++) {
                int s0 = __builtin_ctzll(m0); m0 &= m0 - 1ull;
                float a0 = __uint_as_float((unsigned)__builtin_amdgcn_readlane((int)__float_as_uint(e), s0));
                int pr = __builtin_amdgcn_readlane(cpix, s0);
                denom += a0;
                acc += a0 * bf2f(vhh[(size_t)pr * 32 + d]);
            }
            if (lane < HD)
                att_s[ql * 136 + h * HD + lane] = f2bf(acc / denom);
        }
    }
    __syncthreads();

    // proj: out[tt][o][16px] = att_s[16][128] x Wp^T + b, 8 MFMAs per wave
    int m = lane & 15, quad = lane >> 4;
    int o0 = wv * 32;
    float bb[2][4];
#pragma unroll
    for (int ot = 0; ot < 2; ot++)
#pragma unroll
        for (int reg = 0; reg < 4; reg++) bb[ot][reg] = pb[o0 + ot * 16 + quad * 4 + reg];
    floatx4 pacc[2];
#pragma unroll
    for (int i = 0; i < 2; i++) pacc[i] = (floatx4){0.f, 0.f, 0.f, 0.f};
#pragma unroll
    for (int kc = 0; kc < 4; kc++) {
        short8 a[2], b;
        b = *(const short8*)(&att_s[m * 136 + kc * 32 + quad * 8]);
#pragma unroll
        for (int ot = 0; ot < 2; ot++) {
            a[ot] = *(const short8*)(wp + (o0 + ot * 16 + m) * CH + kc * 32 + quad * 8);
            pacc[ot] = __builtin_amdgcn_mfma_f32_16x16x32_bf16(a[ot], b, pacc[ot], 0, 0, 0);
        }
    }
    int hw0 = qi * WW + qj0;
#pragma unroll
    for (int ot = 0; ot < 2; ot++)
#pragma unroll
        for (int reg = 0; reg < 4; reg++) {
            int o = o0 + ot * 16 + quad * 4 + reg;
            out[((size_t)(tt * CH + o)) * HWS + hw0 + m] = pacc[ot][reg] + bb[ot][reg];
        }
}

extern "C" void kernel_launch(void* const* d_in, const int* in_sizes, int n_in,
                              void* d_out, int out_size, void* d_ws, size_t ws_size,
                              hipStream_t stream) {
    const float* vid    = (const float*)d_in[0];
    const float* wq_dw  = (const float*)d_in[1];
    const float* wq_pw  = (const float*)d_in[2];
    const float* bq     = (const float*)d_in[3];
    const float* wk_dw  = (const float*)d_in[4];
    const float* wk_pw  = (const float*)d_in[5];
    const float* bk     = (const float*)d_in[6];
    const float* wv_dw  = (const float*)d_in[7];
    const float* wv_pw  = (const float*)d_in[8];
    const float* bv     = (const float*)d_in[9];
    const float* proj_w = (const float*)d_in[10];
    const float* proj_b = (const float*)d_in[11];
    float* out = (float*)d_out;

    // workspace (~47.2 MB):
    //   qkf   : 2*QC fp32 [p][c]    (q,k fp32 for attn)
    //   vh    : QC bf16  [4][QTOT][32]  (per-head v gather table)
    //   qk_hi : 2*QC bf16, qk_lo : 2*QC bf16  (dwcvt outputs)
    //   v_bf  : QC bf16
    //   wp_bf : 16384 bf16 (prepped proj weights)
    float* qkf = (float*)d_ws;
    unsigned short* vh = (unsigned short*)(qkf + (size_t)2 * QC);
    unsigned short* qk_hi = vh + (size_t)QC;
    unsigned short* qk_lo = qk_hi + (size_t)2 * QC;
    unsigned short* v_bf = qk_lo + (size_t)2 * QC;
    unsigned short* wp_bf = v_bf + (size_t)QC;

    dwcvt_kernel<<<dim3(QTOT / 64, 4), 256, 0, stream>>>(
        vid, wq_dw, wk_dw, wv_dw, qk_hi, qk_lo, v_bf);
    qkv_mfma<<<dim3(QTOT / 64, 4), 256, 0, stream>>>(
        qk_hi, qk_lo, v_bf, wq_pw, wk_pw, wv_pw, proj_w,
        bq, bk, bv, qkf, vh, wp_bf);
    attnproj_kernel<<<TT * HH * (WW / SEG), 256, 0, stream>>>(
        qkf, qkf + (size_t)QC, vh, wp_bf, proj_b, out);
}

// Round 10
// 203.627 us; speedup vs baseline: 1.0610x; 1.0610x over previous
//
#include <hip/hip_runtime.h>
#include <math.h>

#define TT 2
#define CH 128
#define HH 96
#define WW 96
#define HWS 9216            // H*W
#define QTOT 18432          // T*H*W
#define QC (QTOT*CH)
#define HD 32
#define KTOP 16
#define SCALE 0.17677669529663687f  // 32^-0.5

#define SEG 16              // queries per attn block (one row segment)
#define PR 8                // patch rows
#define PC 23               // patch cols
#define PSTRIDE 36          // floats per patch pixel in LDS

typedef __attribute__((ext_vector_type(8))) short short8;
typedef __attribute__((ext_vector_type(4))) float floatx4;

__device__ __forceinline__ unsigned short f2bf(float f) {
    union { float f; unsigned u; } x; x.f = f;
    unsigned r = x.u + 0x7fffu + ((x.u >> 16) & 1u);
    return (unsigned short)(r >> 16);
}
__device__ __forceinline__ float bf2f(unsigned short h) {
    return __uint_as_float(((unsigned)h) << 16);
}

__device__ __forceinline__ int refl(int x, int n) {
    x = x < 0 ? -x : x;
    return x >= n ? 2 * (n - 1) - x : x;
}

// ------ FUSED depthwise 3x3 + bf16 convert: vid -> qk_hi/lo, v_bf, all [p][c] ---------
__global__ __launch_bounds__(256) void dwcvt_kernel(
    const float* __restrict__ x,
    const float* __restrict__ wq, const float* __restrict__ wk, const float* __restrict__ wv,
    unsigned short* __restrict__ qk_hi,   // [2][p][c]
    unsigned short* __restrict__ qk_lo,   // [2][p][c]
    unsigned short* __restrict__ v_bf)    // [p][c]
{
    int t = threadIdx.x;
    int pl = t & 63;
    int cg = __builtin_amdgcn_readfirstlane(t >> 6);   // wave-uniform channel group
    int p  = blockIdx.x * 64 + pl;
    int c0 = blockIdx.y * 32 + cg * 8;
    int hw = p % HWS;
    int tt = p / HWS;
    int i = hw / WW, j = hw % WW;

    unsigned qh[4], ql[4], kh[4], kl[4], vh4[4];
#pragma unroll
    for (int ic = 0; ic < 8; ic += 2) {
        float sv[3][2];
#pragma unroll
        for (int u = 0; u < 2; u++) {
            int c = c0 + ic + u;
            const float* xp = x + (size_t)(tt * CH + c) * HWS;
            float w0[9], w1[9], w2[9];
#pragma unroll
            for (int r = 0; r < 9; r++) {
                w0[r] = wq[c * 9 + r]; w1[r] = wk[c * 9 + r]; w2[r] = wv[c * 9 + r];
            }
            float s0 = 0.f, s1 = 0.f, s2 = 0.f;
#pragma unroll
            for (int r = 0; r < 3; r++) {
                int ii = i + r - 1;
                if (ii < 0 || ii >= HH) continue;
#pragma unroll
                for (int ss = 0; ss < 3; ss++) {
                    int jj = j + ss - 1;
                    if (jj < 0 || jj >= WW) continue;
                    float xv = xp[ii * WW + jj];
                    s0 += xv * w0[r * 3 + ss];
                    s1 += xv * w1[r * 3 + ss];
                    s2 += xv * w2[r * 3 + ss];
                }
            }
            sv[0][u] = s0; sv[1][u] = s1; sv[2][u] = s2;
        }
        int w = ic >> 1;
        unsigned short h0 = f2bf(sv[0][0]), h1 = f2bf(sv[0][1]);
        qh[w] = h0 | ((unsigned)h1 << 16);
        ql[w] = f2bf(sv[0][0] - bf2f(h0)) | ((unsigned)f2bf(sv[0][1] - bf2f(h1)) << 16);
        h0 = f2bf(sv[1][0]); h1 = f2bf(sv[1][1]);
        kh[w] = h0 | ((unsigned)h1 << 16);
        kl[w] = f2bf(sv[1][0] - bf2f(h0)) | ((unsigned)f2bf(sv[1][1] - bf2f(h1)) << 16);
        vh4[w] = f2bf(sv[2][0]) | ((unsigned)f2bf(sv[2][1]) << 16);
    }
    size_t off = (size_t)p * CH + c0;
    uint4 pk;
    pk.x = qh[0]; pk.y = qh[1]; pk.z = qh[2]; pk.w = qh[3];
    *(uint4*)(qk_hi + off) = pk;
    pk.x = ql[0]; pk.y = ql[1]; pk.z = ql[2]; pk.w = ql[3];
    *(uint4*)(qk_lo + off) = pk;
    pk.x = kh[0]; pk.y = kh[1]; pk.z = kh[2]; pk.w = kh[3];
    *(uint4*)(qk_hi + (size_t)QC + off) = pk;
    pk.x = kl[0]; pk.y = kl[1]; pk.z = kl[2]; pk.w = kl[3];
    *(uint4*)(qk_lo + (size_t)QC + off) = pk;
    pk.x = vh4[0]; pk.y = vh4[1]; pk.z = vh4[2]; pk.w = vh4[3];
    *(uint4*)(v_bf + off) = pk;
}

// ------ ONE dispatch: y=0/1 qk bf16x3 GEMM -> fp32, y=2 v GEMM -> per-head bf16 --------
__global__ __launch_bounds__(256) void qkv_mfma(
    const unsigned short* __restrict__ Ahi,   // [2][p][c]
    const unsigned short* __restrict__ Alo,
    const unsigned short* __restrict__ Avb,   // v_bf [p][c]
    const float* __restrict__ wq_pw, const float* __restrict__ wk_pw,
    const float* __restrict__ wv_pw,
    const float* __restrict__ bq, const float* __restrict__ bk, const float* __restrict__ bv,
    float* __restrict__ qkf,                  // q -> qkf[0], k -> qkf[1] ([p][c] fp32)
    unsigned short* __restrict__ vh)          // [4][QTOT][32] bf16
{
    __shared__ unsigned short WhS[128 * 136];
    __shared__ unsigned short WlS[128 * 136];
    int sel = blockIdx.y;
    int t = threadIdx.x;
    int wv = t >> 6, lane = t & 63;
    int m = lane & 15, quad = lane >> 4;
    int p0 = blockIdx.x * 64;
    int o0 = wv * 32;

    if (sel == 2) {                    // v GEMM (single-pass bf16) -> per-head table
#pragma unroll
        for (int r = 0; r < 16; r++) {
            int lin = r * 256 + t;
            int o = lin >> 5, cq = lin & 31;
            float4 w4 = *(const float4*)(wv_pw + o * CH + cq * 4);
            uint2 pk;
            pk.x = f2bf(w4.x) | ((unsigned)f2bf(w4.y) << 16);
            pk.y = f2bf(w4.z) | ((unsigned)f2bf(w4.w) << 16);
            *(uint2*)(&WhS[o * 136 + cq * 4]) = pk;
        }
        __syncthreads();
        float bb[2];
#pragma unroll
        for (int ot = 0; ot < 2; ot++) bb[ot] = bv[o0 + ot * 16 + m];
        floatx4 acc[4][2];
#pragma unroll
        for (int i = 0; i < 4; i++)
#pragma unroll
            for (int j = 0; j < 2; j++) acc[i][j] = (floatx4){0.f, 0.f, 0.f, 0.f};
#pragma unroll
        for (int kc = 0; kc < 4; kc++) {
            short8 a[4], b[2];
#pragma unroll
            for (int pt = 0; pt < 4; pt++)
                a[pt] = *(const short8*)(Avb + (size_t)(p0 + pt * 16 + m) * CH + kc * 32 + quad * 8);
#pragma unroll
            for (int ot = 0; ot < 2; ot++)
                b[ot] = *(const short8*)(&WhS[(o0 + ot * 16 + m) * 136 + kc * 32 + quad * 8]);
#pragma unroll
            for (int pt = 0; pt < 4; pt++)
#pragma unroll
                for (int ot = 0; ot < 2; ot++)
                    acc[pt][ot] = __builtin_amdgcn_mfma_f32_16x16x32_bf16(a[pt], b[ot], acc[pt][ot], 0, 0, 0);
        }
        // epilogue: head h = wv (c = wv*32 + ot*16 + m), per-head gather layout
        unsigned short* vhh = vh + (size_t)wv * QTOT * 32;
#pragma unroll
        for (int pt = 0; pt < 4; pt++)
#pragma unroll
            for (int ot = 0; ot < 2; ot++)
#pragma unroll
                for (int reg = 0; reg < 4; reg++) {
                    int p = p0 + pt * 16 + quad * 4 + reg;
                    vhh[(size_t)p * 32 + ot * 16 + m] = f2bf(acc[pt][ot][reg] + bb[ot]);
                }
        return;
    }

    // sel 0/1: q,k via bf16x3 split (fp32-emulating)
    const float* W = sel ? wk_pw : wq_pw;
    const float* bias = sel ? bk : bq;
    float scale = sel ? 1.f : SCALE;
    const unsigned short* ah = Ahi + (size_t)sel * QC;
    const unsigned short* al = Alo + (size_t)sel * QC;
    float* O = qkf + (size_t)sel * QC;

#pragma unroll
    for (int r = 0; r < 16; r++) {
        int lin = r * 256 + t;
        int o = lin >> 5, cq = lin & 31;
        float4 w4 = *(const float4*)(W + o * CH + cq * 4);
        unsigned short hx = f2bf(w4.x), hy = f2bf(w4.y), hz = f2bf(w4.z), hw = f2bf(w4.w);
        unsigned short lx = f2bf(w4.x - bf2f(hx)), ly = f2bf(w4.y - bf2f(hy));
        unsigned short lz = f2bf(w4.z - bf2f(hz)), lw = f2bf(w4.w - bf2f(hw));
        uint2 pk;
        pk.x = hx | ((unsigned)hy << 16); pk.y = hz | ((unsigned)hw << 16);
        *(uint2*)(&WhS[o * 136 + cq * 4]) = pk;
        pk.x = lx | ((unsigned)ly << 16); pk.y = lz | ((unsigned)lw << 16);
        *(uint2*)(&WlS[o * 136 + cq * 4]) = pk;
    }
    __syncthreads();
    float bb[2];
#pragma unroll
    for (int ot = 0; ot < 2; ot++) bb[ot] = bias[o0 + ot * 16 + m];
    floatx4 acc[4][2];
#pragma unroll
    for (int i = 0; i < 4; i++)
#pragma unroll
        for (int j = 0; j < 2; j++) acc[i][j] = (floatx4){0.f, 0.f, 0.f, 0.f};
#pragma unroll
    for (int kc = 0; kc < 4; kc++) {
        short8 avh[4], avl[4], bh[2], bl[2];
#pragma unroll
        for (int pt = 0; pt < 4; pt++) {
            size_t base = (size_t)(p0 + pt * 16 + m) * CH + kc * 32 + quad * 8;
            avh[pt] = *(const short8*)(ah + base);
            avl[pt] = *(const short8*)(al + base);
        }
#pragma unroll
        for (int ot = 0; ot < 2; ot++) {
            int lidx = (o0 + ot * 16 + m) * 136 + kc * 32 + quad * 8;
            bh[ot] = *(const short8*)(&WhS[lidx]);
            bl[ot] = *(const short8*)(&WlS[lidx]);
        }
#pragma unroll
        for (int pt = 0; pt < 4; pt++)
#pragma unroll
            for (int ot = 0; ot < 2; ot++) {
                acc[pt][ot] = __builtin_amdgcn_mfma_f32_16x16x32_bf16(avh[pt], bh[ot], acc[pt][ot], 0, 0, 0);
                acc[pt][ot] = __builtin_amdgcn_mfma_f32_16x16x32_bf16(avh[pt], bl[ot], acc[pt][ot], 0, 0, 0);
                acc[pt][ot] = __builtin_amdgcn_mfma_f32_16x16x32_bf16(avl[pt], bh[ot], acc[pt][ot], 0, 0, 0);
            }
    }
#pragma unroll
    for (int pt = 0; pt < 4; pt++)
#pragma unroll
        for (int ot = 0; ot < 2; ot++)
#pragma unroll
            for (int reg = 0; reg < 4; reg++) {
                int p = p0 + pt * 16 + quad * 4 + reg;
                O[(size_t)p * CH + o0 + ot * 16 + m] = (acc[pt][ot][reg] + bb[ot]) * scale;
            }
}

// ------ attention (R8 structure): LDS k-patch, per-head grid, bf16 v-table gather ------
__global__ __launch_bounds__(256) void attn_kernel(
    const float* __restrict__ q,    // qkf[0] [p][128] fp32
    const float* __restrict__ k,    // qkf[1]
    const unsigned short* __restrict__ vh,   // [4][QTOT][32] bf16
    unsigned short* __restrict__ att)        // [p][128] bf16
{
    __shared__ float kp[PR * PC * PSTRIDE];   // 26.5 KB
    int h = blockIdx.y;
    int n = blockIdx.x;
    int seg = (n & 7) * 144 + (n >> 3);       // XCD-band swizzle
    int qj0 = (seg % (WW / SEG)) * SEG;
    int qi = (seg / (WW / SEG)) % HH;
    int tt = seg / ((WW / SEG) * HH);
    int t = threadIdx.x;

    // stage reflected k patch: coalesced
#pragma unroll
    for (int r = 0; r < 6; r++) {
        int f = r * 256 + t;
        if (f < PR * PC * 8) {
            int pix = f >> 3, d4 = f & 7;
            int ci = pix / PC, cj = pix - ci * PC;
            int gi = refl(qi + ci - 4, HH);
            int gj = refl(qj0 + cj - 4, WW);
            int gp = tt * HWS + gi * WW + gj;
            *(float4*)(&kp[pix * PSTRIDE + d4 * 4]) =
                *(const float4*)(k + (size_t)gp * CH + h * HD + d4 * 4);
        }
    }
    __syncthreads();

    int wv = t >> 6, lane = t & 63;
    int ci = lane >> 3, cjo = lane & 7;
    int di = ci - 4, dj = cjo - 4;
    int rowoff = tt * HWS + refl(qi + di, HH) * WW;
    const int d = lane & (HD - 1);
    const unsigned long long below = (1ull << lane) - 1ull;
    const unsigned short* vhh = vh + (size_t)h * QTOT * 32;

    for (int ql = wv * 4; ql < wv * 4 + 4; ql++) {
        int qj = qj0 + ql;
        int p = tt * HWS + qi * WW + qj;
        const float* qp = q + (size_t)p * CH + h * HD;
        const float* kr = &kp[(ci * PC + ql + cjo) * PSTRIDE];
        float dist = 0.f;
#pragma unroll
        for (int dd = 0; dd < 8; dd++) {
            float4 qv = *(const float4*)(qp + dd * 4);
            float4 kv = *(const float4*)(kr + dd * 4);
            dist += qv.x * kv.x + qv.y * kv.y + qv.z * kv.z + qv.w * kv.w;
        }
        int cpix = rowoff + refl(qj + dj, WW);

        // order-preserving uint key (desc select)
        unsigned u = __float_as_uint(dist);
        unsigned key = (u & 0x80000000u) ? ~u : (u | 0x80000000u);

        // fixed-32 branch-free radix select of the 16th-largest key
        unsigned prefix = 0u;
        int need = KTOP;
#pragma unroll
        for (int bit = 31; bit >= 0; --bit) {
            unsigned hi = (prefix >> bit) | 1u;
            unsigned long long b = __ballot((key >> bit) == hi);
            int cnt = __popcll(b);
            bool take = cnt >= need;
            prefix = take ? (prefix | (1u << bit)) : prefix;
            need = take ? need : need - cnt;
        }
        // selection set: key > kth, plus first `need` of tie class by lane asc
        bool isEq = (key == prefix);
        unsigned long long eqm = __ballot(isEq);
        int rk = __popcll(eqm & below);
        bool selb = (key > prefix) || (isEq && rk < need);
        unsigned long long selm = __ballot(selb);

        // softmax without shift: dists are O(1e-3), exp is exact-safe
        float e = selb ? __expf(dist) : 0.f;

        // walk 16 selected lanes: scalar ctz + readlane, 64B-line v gather
        float acc = 0.f, denom = 0.f;
        unsigned long long m0 = selm;
#pragma unroll
        for (int r = 0; r < KTOP; r++) {
            int s0 = __builtin_ctzll(m0); m0 &= m0 - 1ull;
            float a0 = __uint_as_float((unsigned)__builtin_amdgcn_readlane((int)__float_as_uint(e), s0));
            int pr = __builtin_amdgcn_readlane(cpix, s0);
            denom += a0;
            acc += a0 * bf2f(vhh[(size_t)pr * 32 + d]);
        }
        if (lane < HD)
            att[(size_t)p * CH + h * HD + lane] = f2bf(acc / denom);
    }
}

// ---------------- proj via bf16 MFMA (64-px blocks, in-kernel LDS W conversion) --------
__global__ __launch_bounds__(256) void proj_mfma(
    const unsigned short* __restrict__ A,   // att_bf [p][c] bf16
    const float* __restrict__ W,            // proj_w [o][c] fp32
    const float* __restrict__ bias,
    float* __restrict__ out)                // NCHW fp32
{
    __shared__ unsigned short Ws[128 * 136];
    int t = threadIdx.x;
#pragma unroll
    for (int r = 0; r < 16; r++) {
        int lin = r * 256 + t;
        int o = lin >> 5, cq = lin & 31;
        float4 w4 = *(const float4*)(W + o * CH + cq * 4);
        uint2 pk;
        pk.x = f2bf(w4.x) | ((unsigned)f2bf(w4.y) << 16);
        pk.y = f2bf(w4.z) | ((unsigned)f2bf(w4.w) << 16);
        *(uint2*)(&Ws[o * 136 + cq * 4]) = pk;
    }
    __syncthreads();
    int wv = t >> 6, lane = t & 63;
    int m = lane & 15, quad = lane >> 4;
    int p0 = blockIdx.x * 64;
    int o0 = wv * 32;
    float bb[2][4];
#pragma unroll
    for (int ot = 0; ot < 2; ot++)
#pragma unroll
        for (int reg = 0; reg < 4; reg++) bb[ot][reg] = bias[o0 + ot * 16 + quad * 4 + reg];
    floatx4 acc[2][4];
#pragma unroll
    for (int i = 0; i < 2; i++)
#pragma unroll
        for (int j = 0; j < 4; j++) acc[i][j] = (floatx4){0.f, 0.f, 0.f, 0.f};
#pragma unroll
    for (int kc = 0; kc < 4; kc++) {
        short8 a[2], b[4];
#pragma unroll
        for (int ot = 0; ot < 2; ot++)
            a[ot] = *(const short8*)(&Ws[(o0 + ot * 16 + m) * 136 + kc * 32 + quad * 8]);
#pragma unroll
        for (int pt = 0; pt < 4; pt++)
            b[pt] = *(const short8*)(A + (size_t)(p0 + pt * 16 + m) * CH + kc * 32 + quad * 8);
#pragma unroll
        for (int ot = 0; ot < 2; ot++)
#pragma unroll
            for (int pt = 0; pt < 4; pt++)
                acc[ot][pt] = __builtin_amdgcn_mfma_f32_16x16x32_bf16(a[ot], b[pt], acc[ot][pt], 0, 0, 0);
    }
    int tt = p0 / HWS;
    int hwb = p0 - tt * HWS;
#pragma unroll
    for (int ot = 0; ot < 2; ot++)
#pragma unroll
        for (int pt = 0; pt < 4; pt++)
#pragma unroll
            for (int reg = 0; reg < 4; reg++) {
                int o = o0 + ot * 16 + quad * 4 + reg;
                int hw = hwb + pt * 16 + m;
                out[((size_t)(tt * CH + o)) * HWS + hw] = acc[ot][pt][reg] + bb[ot][reg];
            }
}

extern "C" void kernel_launch(void* const* d_in, const int* in_sizes, int n_in,
                              void* d_out, int out_size, void* d_ws, size_t ws_size,
                              hipStream_t stream) {
    const float* vid    = (const float*)d_in[0];
    const float* wq_dw  = (const float*)d_in[1];
    const float* wq_pw  = (const float*)d_in[2];
    const float* bq     = (const float*)d_in[3];
    const float* wk_dw  = (const float*)d_in[4];
    const float* wk_pw  = (const float*)d_in[5];
    const float* bk     = (const float*)d_in[6];
    const float* wv_dw  = (const float*)d_in[7];
    const float* wv_pw  = (const float*)d_in[8];
    const float* bv     = (const float*)d_in[9];
    const float* proj_w = (const float*)d_in[10];
    const float* proj_b = (const float*)d_in[11];
    float* out = (float*)d_out;

    // workspace (~47.2 MB):
    //   qkf   : 2*QC fp32 [p][c]    (q,k fp32 for attn)
    //   vh    : QC bf16 [4][QTOT][32]  (per-head v gather table)
    //   qk_hi : 2*QC bf16, qk_lo : 2*QC bf16  (dwcvt outputs)
    //   v_bf  : QC bf16 (aliased as att_bf once qkv_mfma has consumed it)
    float* qkf = (float*)d_ws;
    unsigned short* vh = (unsigned short*)(qkf + (size_t)2 * QC);
    unsigned short* qk_hi = vh + (size_t)QC;
    unsigned short* qk_lo = qk_hi + (size_t)2 * QC;
    unsigned short* v_bf = qk_lo + (size_t)2 * QC;
    unsigned short* att_bf = v_bf;

    dwcvt_kernel<<<dim3(QTOT / 64, 4), 256, 0, stream>>>(
        vid, wq_dw, wk_dw, wv_dw, qk_hi, qk_lo, v_bf);
    qkv_mfma<<<dim3(QTOT / 64, 3), 256, 0, stream>>>(
        qk_hi, qk_lo, v_bf, wq_pw, wk_pw, wv_pw, bq, bk, bv, qkf, vh);
    attn_kernel<<<dim3(TT * HH * (WW / SEG), 4), 256, 0, stream>>>(
        qkf, qkf + (size_t)QC, vh, att_bf);
    proj_mfma<<<QTOT / 64, 256, 0, stream>>>(att_bf, proj_w, proj_b, out);
}

// Round 13
// 192.649 us; speedup vs baseline: 1.1215x; 1.0570x over previous
//
#include <hip/hip_runtime.h>
#include <math.h>

#define TT 2
#define CH 128
#define HH 96
#define WW 96
#define HWS 9216            // H*W
#define QTOT 18432          // T*H*W
#define QC (QTOT*CH)
#define HD 32
#define KTOP 16
#define SCALE 0.17677669529663687f  // 32^-0.5

#define SEG 16              // queries per attn block (one row segment)
#define PR 8                // patch rows
#define PC 23               // patch cols
#define PSTRIDE 36          // floats per patch pixel in LDS

// wbuf (bf16 shorts): wq_hi@0 wq_lo@16384 wk_hi@32768 wk_lo@49152 wv_hi@65536 pj_hi@81920
#define WB_TOT 98304

typedef __attribute__((ext_vector_type(8))) short short8;
typedef __attribute__((ext_vector_type(4))) float floatx4;

__device__ __forceinline__ unsigned short f2bf(float f) {
    union { float f; unsigned u; } x; x.f = f;
    unsigned r = x.u + 0x7fffu + ((x.u >> 16) & 1u);
    return (unsigned short)(r >> 16);
}
__device__ __forceinline__ float bf2f(unsigned short h) {
    return __uint_as_float(((unsigned)h) << 16);
}

__device__ __forceinline__ int refl(int x, int n) {
    x = x < 0 ? -x : x;
    return x >= n ? 2 * (n - 1) - x : x;
}

// ------ FUSED depthwise 3x3 + bf16 convert; block x==288 does pointwise-W prep ---------
__global__ __launch_bounds__(256) void dwcvt_kernel(
    const float* __restrict__ x,
    const float* __restrict__ wq, const float* __restrict__ wk, const float* __restrict__ wv,
    const float* __restrict__ wq_pw, const float* __restrict__ wk_pw,
    const float* __restrict__ wv_pw, const float* __restrict__ proj_w,
    unsigned short* __restrict__ qk_hi,   // [2][p][c]
    unsigned short* __restrict__ qk_lo,   // [2][p][c]
    unsigned short* __restrict__ v_bf,    // [p][c]
    unsigned short* __restrict__ wbuf)
{
    int t = threadIdx.x;
    if (blockIdx.x == 288) {              // one-shot weight conversion
        int y = blockIdx.y;               // 0=wq_pw(hi+lo) 1=wk_pw(hi+lo) 2=wv_pw 3=proj_w
        const float* src = y == 0 ? wq_pw : (y == 1 ? wk_pw : (y == 2 ? wv_pw : proj_w));
        unsigned short* hi = wbuf + (y == 0 ? 0 : (y == 1 ? 32768 : (y == 2 ? 65536 : 81920)));
#pragma unroll
        for (int r = 0; r < 16; r++) {
            int idx = r * 256 + t;        // float4 index, 4096 total = 128x128
            float4 w4 = *(const float4*)(src + idx * 4);
            unsigned short hx = f2bf(w4.x), hy = f2bf(w4.y), hz = f2bf(w4.z), hw = f2bf(w4.w);
            uint2 pk;
            pk.x = hx | ((unsigned)hy << 16); pk.y = hz | ((unsigned)hw << 16);
            *(uint2*)(hi + idx * 4) = pk;
            if (y < 2) {
                unsigned short lx = f2bf(w4.x - bf2f(hx)), ly = f2bf(w4.y - bf2f(hy));
                unsigned short lz = f2bf(w4.z - bf2f(hz)), lw = f2bf(w4.w - bf2f(hw));
                pk.x = lx | ((unsigned)ly << 16); pk.y = lz | ((unsigned)lw << 16);
                *(uint2*)(hi + 16384 + idx * 4) = pk;
            }
        }
        return;
    }

    int pl = t & 63;
    int cg = __builtin_amdgcn_readfirstlane(t >> 6);   // wave-uniform channel group
    int p  = blockIdx.x * 64 + pl;
    int c0 = blockIdx.y * 32 + cg * 8;
    int hw = p % HWS;
    int tt = p / HWS;
    int i = hw / WW, j = hw % WW;

    unsigned qh[4], ql[4], kh[4], kl[4], vh4[4];
#pragma unroll
    for (int ic = 0; ic < 8; ic += 2) {
        float sv[3][2];
#pragma unroll
        for (int u = 0; u < 2; u++) {
            int c = c0 + ic + u;
            const float* xp = x + (size_t)(tt * CH + c) * HWS;
            float w0[9], w1[9], w2[9];
#pragma unroll
            for (int r = 0; r < 9; r++) {
                w0[r] = wq[c * 9 + r]; w1[r] = wk[c * 9 + r]; w2[r] = wv[c * 9 + r];
            }
            float s0 = 0.f, s1 = 0.f, s2 = 0.f;
#pragma unroll
            for (int r = 0; r < 3; r++) {
                int ii = i + r - 1;
                if (ii < 0 || ii >= HH) continue;
#pragma unroll
                for (int ss = 0; ss < 3; ss++) {
                    int jj = j + ss - 1;
                    if (jj < 0 || jj >= WW) continue;
                    float xv = xp[ii * WW + jj];
                    s0 += xv * w0[r * 3 + ss];
                    s1 += xv * w1[r * 3 + ss];
                    s2 += xv * w2[r * 3 + ss];
                }
            }
            sv[0][u] = s0; sv[1][u] = s1; sv[2][u] = s2;
        }
        int w = ic >> 1;
        unsigned short h0 = f2bf(sv[0][0]), h1 = f2bf(sv[0][1]);
        qh[w] = h0 | ((unsigned)h1 << 16);
        ql[w] = f2bf(sv[0][0] - bf2f(h0)) | ((unsigned)f2bf(sv[0][1] - bf2f(h1)) << 16);
        h0 = f2bf(sv[1][0]); h1 = f2bf(sv[1][1]);
        kh[w] = h0 | ((unsigned)h1 << 16);
        kl[w] = f2bf(sv[1][0] - bf2f(h0)) | ((unsigned)f2bf(sv[1][1] - bf2f(h1)) << 16);
        vh4[w] = f2bf(sv[2][0]) | ((unsigned)f2bf(sv[2][1]) << 16);
    }
    size_t off = (size_t)p * CH + c0;
    uint4 pk;
    pk.x = qh[0]; pk.y = qh[1]; pk.z = qh[2]; pk.w = qh[3];
    *(uint4*)(qk_hi + off) = pk;
    pk.x = ql[0]; pk.y = ql[1]; pk.z = ql[2]; pk.w = ql[3];
    *(uint4*)(qk_lo + off) = pk;
    pk.x = kh[0]; pk.y = kh[1]; pk.z = kh[2]; pk.w = kh[3];
    *(uint4*)(qk_hi + (size_t)QC + off) = pk;
    pk.x = kl[0]; pk.y = kl[1]; pk.z = kl[2]; pk.w = kl[3];
    *(uint4*)(qk_lo + (size_t)QC + off) = pk;
    pk.x = vh4[0]; pk.y = vh4[1]; pk.z = vh4[2]; pk.w = vh4[3];
    *(uint4*)(v_bf + off) = pk;
}

// ------ ONE dispatch: y=0/1 qk bf16x3 GEMM -> fp32, y=2 v GEMM -> per-head bf16 --------
__global__ __launch_bounds__(256) void qkv_mfma(
    const unsigned short* __restrict__ Ahi,   // [2][p][c]
    const unsigned short* __restrict__ Alo,
    const unsigned short* __restrict__ Avb,   // v_bf [p][c]
    const unsigned short* __restrict__ wbuf,  // prepped bf16 weights
    const float* __restrict__ bq, const float* __restrict__ bk, const float* __restrict__ bv,
    float* __restrict__ qkf,                  // q -> qkf[0], k -> qkf[1] ([p][c] fp32)
    unsigned short* __restrict__ vh)          // [4][QTOT][32] bf16
{
    __shared__ unsigned short WhS[128 * 136];
    __shared__ unsigned short WlS[128 * 136];
    int sel = blockIdx.y;
    int t = threadIdx.x;
    int wv = t >> 6, lane = t & 63;
    int m = lane & 15, quad = lane >> 4;
    int p0 = blockIdx.x * 64;
    int o0 = wv * 32;

    if (sel == 2) {                    // v GEMM -> per-head table
        const unsigned short* Wg = wbuf + 65536;
#pragma unroll
        for (int r = 0; r < 16; r++) {
            int lin = r * 256 + t;
            int o = lin >> 5, cq = lin & 31;
            *(uint2*)(&WhS[o * 136 + cq * 4]) = *(const uint2*)(Wg + o * CH + cq * 4);
        }
        __syncthreads();
        float bb[2];
#pragma unroll
        for (int ot = 0; ot < 2; ot++) bb[ot] = bv[o0 + ot * 16 + m];
        floatx4 acc[4][2];
#pragma unroll
        for (int i = 0; i < 4; i++)
#pragma unroll
            for (int j = 0; j < 2; j++) acc[i][j] = (floatx4){0.f, 0.f, 0.f, 0.f};
#pragma unroll
        for (int kc = 0; kc < 4; kc++) {
            short8 a[4], b[2];
#pragma unroll
            for (int pt = 0; pt < 4; pt++)
                a[pt] = *(const short8*)(Avb + (size_t)(p0 + pt * 16 + m) * CH + kc * 32 + quad * 8);
#pragma unroll
            for (int ot = 0; ot < 2; ot++)
                b[ot] = *(const short8*)(&WhS[(o0 + ot * 16 + m) * 136 + kc * 32 + quad * 8]);
#pragma unroll
            for (int pt = 0; pt < 4; pt++)
#pragma unroll
                for (int ot = 0; ot < 2; ot++)
                    acc[pt][ot] = __builtin_amdgcn_mfma_f32_16x16x32_bf16(a[pt], b[ot], acc[pt][ot], 0, 0, 0);
        }
        unsigned short* vhh = vh + (size_t)wv * QTOT * 32;   // head = wv
#pragma unroll
        for (int pt = 0; pt < 4; pt++)
#pragma unroll
            for (int ot = 0; ot < 2; ot++)
#pragma unroll
                for (int reg = 0; reg < 4; reg++) {
                    int p = p0 + pt * 16 + quad * 4 + reg;
                    vhh[(size_t)p * 32 + ot * 16 + m] = f2bf(acc[pt][ot][reg] + bb[ot]);
                }
        return;
    }

    // sel 0/1: q,k via bf16x3 split (fp32-emulating)
    const unsigned short* Wh_g = wbuf + sel * 32768;
    const unsigned short* Wl_g = Wh_g + 16384;
    const float* bias = sel ? bk : bq;
    float scale = sel ? 1.f : SCALE;
    const unsigned short* ah = Ahi + (size_t)sel * QC;
    const unsigned short* al = Alo + (size_t)sel * QC;
    float* O = qkf + (size_t)sel * QC;

#pragma unroll
    for (int r = 0; r < 16; r++) {
        int lin = r * 256 + t;
        int o = lin >> 5, cq = lin & 31;
        *(uint2*)(&WhS[o * 136 + cq * 4]) = *(const uint2*)(Wh_g + o * CH + cq * 4);
        *(uint2*)(&WlS[o * 136 + cq * 4]) = *(const uint2*)(Wl_g + o * CH + cq * 4);
    }
    __syncthreads();
    float bb[2];
#pragma unroll
    for (int ot = 0; ot < 2; ot++) bb[ot] = bias[o0 + ot * 16 + m];
    floatx4 acc[4][2];
#pragma unroll
    for (int i = 0; i < 4; i++)
#pragma unroll
        for (int j = 0; j < 2; j++) acc[i][j] = (floatx4){0.f, 0.f, 0.f, 0.f};
#pragma unroll
    for (int kc = 0; kc < 4; kc++) {
        short8 avh[4], avl[4], bh[2], bl[2];
#pragma unroll
        for (int pt = 0; pt < 4; pt++) {
            size_t base = (size_t)(p0 + pt * 16 + m) * CH + kc * 32 + quad * 8;
            avh[pt] = *(const short8*)(ah + base);
            avl[pt] = *(const short8*)(al + base);
        }
#pragma unroll
        for (int ot = 0; ot < 2; ot++) {
            int lidx = (o0 + ot * 16 + m) * 136 + kc * 32 + quad * 8;
            bh[ot] = *(const short8*)(&WhS[lidx]);
            bl[ot] = *(const short8*)(&WlS[lidx]);
        }
#pragma unroll
        for (int pt = 0; pt < 4; pt++)
#pragma unroll
            for (int ot = 0; ot < 2; ot++) {
                acc[pt][ot] = __builtin_amdgcn_mfma_f32_16x16x32_bf16(avh[pt], bh[ot], acc[pt][ot], 0, 0, 0);
                acc[pt][ot] = __builtin_amdgcn_mfma_f32_16x16x32_bf16(avh[pt], bl[ot], acc[pt][ot], 0, 0, 0);
                acc[pt][ot] = __builtin_amdgcn_mfma_f32_16x16x32_bf16(avl[pt], bh[ot], acc[pt][ot], 0, 0, 0);
            }
    }
#pragma unroll
    for (int pt = 0; pt < 4; pt++)
#pragma unroll
        for (int ot = 0; ot < 2; ot++)
#pragma unroll
            for (int reg = 0; reg < 4; reg++) {
                int p = p0 + pt * 16 + quad * 4 + reg;
                O[(size_t)p * CH + o0 + ot * 16 + m] = (acc[pt][ot][reg] + bb[ot]) * scale;
            }
}

// ------ attention: LDS k-patch, per-head grid, zero-inited LDS-compacted gather --------
__global__ __launch_bounds__(256) void attn_kernel(
    const float* __restrict__ q,    // qkf[0] [p][128] fp32
    const float* __restrict__ k,    // qkf[1]
    const unsigned short* __restrict__ vh,   // [4][QTOT][32] bf16
    unsigned short* __restrict__ att)        // [p][128] bf16
{
    __shared__ float kp[PR * PC * PSTRIDE];   // 26.5 KB
    __shared__ uint2 slot[4][16];             // per-wave (e, cpix) compaction, 512 B
    int h = blockIdx.y;
    int n = blockIdx.x;
    int seg = (n & 7) * 144 + (n >> 3);       // XCD-band swizzle
    int qj0 = (seg % (WW / SEG)) * SEG;
    int qi = (seg / (WW / SEG)) % HH;
    int tt = seg / ((WW / SEG) * HH);
    int t = threadIdx.x;

    // stage reflected k patch: coalesced
#pragma unroll
    for (int r = 0; r < 6; r++) {
        int f = r * 256 + t;
        if (f < PR * PC * 8) {
            int pix = f >> 3, d4 = f & 7;
            int ci = pix / PC, cj = pix - ci * PC;
            int gi = refl(qi + ci - 4, HH);
            int gj = refl(qj0 + cj - 4, WW);
            int gp = tt * HWS + gi * WW + gj;
            *(float4*)(&kp[pix * PSTRIDE + d4 * 4]) =
                *(const float4*)(k + (size_t)gp * CH + h * HD + d4 * 4);
        }
    }

    int wv = t >> 6, lane = t & 63;
    // defensive zero-init: an unwritten slot then contributes 0 and gathers pixel 0
    if (lane < KTOP) slot[wv][lane] = make_uint2(0u, 0u);
    __syncthreads();

    int ci = lane >> 3, cjo = lane & 7;
    int di = ci - 4, dj = cjo - 4;
    int rowoff = tt * HWS + refl(qi + di, HH) * WW;
    const int d = lane & (HD - 1);
    const unsigned long long below = (1ull << lane) - 1ull;
    const unsigned short* vhh = vh + (size_t)h * QTOT * 32;

    for (int ql = wv * 4; ql < wv * 4 + 4; ql++) {
        int qj = qj0 + ql;
        int p = tt * HWS + qi * WW + qj;
        const float* qp = q + (size_t)p * CH + h * HD;
        const float* kr = &kp[(ci * PC + ql + cjo) * PSTRIDE];
        float dist = 0.f;
#pragma unroll
        for (int dd = 0; dd < 8; dd++) {
            float4 qv = *(const float4*)(qp + dd * 4);
            float4 kv = *(const float4*)(kr + dd * 4);
            dist += qv.x * kv.x + qv.y * kv.y + qv.z * kv.z + qv.w * kv.w;
        }
        int cpix = rowoff + refl(qj + dj, WW);

        // order-preserving uint key (desc select)
        unsigned u = __float_as_uint(dist);
        unsigned key = (u & 0x80000000u) ? ~u : (u | 0x80000000u);

        // fixed-32 branch-free radix select of the 16th-largest key
        unsigned prefix = 0u;
        int need = KTOP;
#pragma unroll
        for (int bit = 31; bit >= 0; --bit) {
            unsigned hi = (prefix >> bit) | 1u;
            unsigned long long b = __ballot((key >> bit) == hi);
            int cnt = __popcll(b);
            bool take = cnt >= need;
            prefix = take ? (prefix | (1u << bit)) : prefix;
            need = take ? need : need - cnt;
        }
        // selection set: key > kth, plus first `need` of tie class by lane asc
        bool isEq = (key == prefix);
        unsigned long long eqm = __ballot(isEq);
        int rk = __popcll(eqm & below);
        bool selb = (key > prefix) || (isEq && rk < need);
        unsigned long long selm = __ballot(selb);

        // softmax without shift: dists are O(1e-3), exp is exact-safe
        float e = selb ? __expf(dist) : 0.f;

        // compact selected (e, cpix) to per-wave LDS slots in lane-ascending rank order
        int rksel = __builtin_amdgcn_mbcnt_hi(
            (unsigned)(selm >> 32), __builtin_amdgcn_mbcnt_lo((unsigned)selm, 0));
        if (selb && rksel < KTOP) slot[wv][rksel] = make_uint2(__float_as_uint(e), (unsigned)cpix);

        // 16 broadcast ds_read_b64 (no serial SALU chain), order identical to ctz walk
        float acc = 0.f, denom = 0.f;
#pragma unroll
        for (int r = 0; r < KTOP; r++) {
            uint2 sp = slot[wv][r];
            float a0 = __uint_as_float(sp.x);
            denom += a0;
            acc += a0 * bf2f(vhh[(size_t)sp.y * 32 + d]);
        }
        if (lane < HD)
            att[(size_t)p * CH + h * HD + lane] = f2bf(acc / denom);
    }
}

// ---------------- proj via bf16 MFMA (64-px blocks, prepped weights) ----------------
__global__ __launch_bounds__(256) void proj_mfma(
    const unsigned short* __restrict__ A,   // att_bf [p][c] bf16
    const unsigned short* __restrict__ wbuf,
    const float* __restrict__ bias,
    float* __restrict__ out)                // NCHW fp32
{
    __shared__ unsigned short Ws[128 * 136];
    const unsigned short* Wg = wbuf + 81920;
    int t = threadIdx.x;
#pragma unroll
    for (int r = 0; r < 16; r++) {
        int lin = r * 256 + t;
        int o = lin >> 5, cq = lin & 31;
        *(uint2*)(&Ws[o * 136 + cq * 4]) = *(const uint2*)(Wg + o * CH + cq * 4);
    }
    __syncthreads();
    int wv = t >> 6, lane = t & 63;
    int m = lane & 15, quad = lane >> 4;
    int p0 = blockIdx.x * 64;
    int o0 = wv * 32;
    float bb[2][4];
#pragma unroll
    for (int ot = 0; ot < 2; ot++)
#pragma unroll
        for (int reg = 0; reg < 4; reg++) bb[ot][reg] = bias[o0 + ot * 16 + quad * 4 + reg];
    floatx4 acc[2][4];
#pragma unroll
    for (int i = 0; i < 2; i++)
#pragma unroll
        for (int j = 0; j < 4; j++) acc[i][j] = (floatx4){0.f, 0.f, 0.f, 0.f};
#pragma unroll
    for (int kc = 0; kc < 4; kc++) {
        short8 a[2], b[4];
#pragma unroll
        for (int ot = 0; ot < 2; ot++)
            a[ot] = *(const short8*)(&Ws[(o0 + ot * 16 + m) * 136 + kc * 32 + quad * 8]);
#pragma unroll
        for (int pt = 0; pt < 4; pt++)
            b[pt] = *(const short8*)(A + (size_t)(p0 + pt * 16 + m) * CH + kc * 32 + quad * 8);
#pragma unroll
        for (int ot = 0; ot < 2; ot++)
#pragma unroll
            for (int pt = 0; pt < 4; pt++)
                acc[ot][pt] = __builtin_amdgcn_mfma_f32_16x16x32_bf16(a[ot], b[pt], acc[ot][pt], 0, 0, 0);
    }
    int tt = p0 / HWS;
    int hwb = p0 - tt * HWS;
#pragma unroll
    for (int ot = 0; ot < 2; ot++)
#pragma unroll
        for (int pt = 0; pt < 4; pt++)
#pragma unroll
            for (int reg = 0; reg < 4; reg++) {
                int o = o0 + ot * 16 + quad * 4 + reg;
                int hw = hwb + pt * 16 + m;
                out[((size_t)(tt * CH + o)) * HWS + hw] = acc[ot][pt][reg] + bb[ot][reg];
            }
}

extern "C" void kernel_launch(void* const* d_in, const int* in_sizes, int n_in,
                              void* d_out, int out_size, void* d_ws, size_t ws_size,
                              hipStream_t stream) {
    const float* vid    = (const float*)d_in[0];
    const float* wq_dw  = (const float*)d_in[1];
    const float* wq_pw  = (const float*)d_in[2];
    const float* bq     = (const float*)d_in[3];
    const float* wk_dw  = (const float*)d_in[4];
    const float* wk_pw  = (const float*)d_in[5];
    const float* bk     = (const float*)d_in[6];
    const float* wv_dw  = (const float*)d_in[7];
    const float* wv_pw  = (const float*)d_in[8];
    const float* bv     = (const float*)d_in[9];
    const float* proj_w = (const float*)d_in[10];
    const float* proj_b = (const float*)d_in[11];
    float* out = (float*)d_out;

    // workspace (~47.3 MB):
    //   qkf   : 2*QC fp32 [p][c]
    //   vh    : QC bf16 [4][QTOT][32]
    //   qk_hi : 2*QC bf16, qk_lo : 2*QC bf16
    //   v_bf  : QC bf16 (aliased as att_bf after qkv_mfma consumes it)
    //   wbuf  : WB_TOT bf16 prepped pointwise/proj weights
    float* qkf = (float*)d_ws;
    unsigned short* vh = (unsigned short*)(qkf + (size_t)2 * QC);
    unsigned short* qk_hi = vh + (size_t)QC;
    unsigned short* qk_lo = qk_hi + (size_t)2 * QC;
    unsigned short* v_bf = qk_lo + (size_t)2 * QC;
    unsigned short* wbuf = v_bf + (size_t)QC;
    unsigned short* att_bf = v_bf;

    dwcvt_kernel<<<dim3(289, 4), 256, 0, stream>>>(
        vid, wq_dw, wk_dw, wv_dw, wq_pw, wk_pw, wv_pw, proj_w,
        qk_hi, qk_lo, v_bf, wbuf);
    qkv_mfma<<<dim3(QTOT / 64, 3), 256, 0, stream>>>(
        qk_hi, qk_lo, v_bf, wbuf, bq, bk, bv, qkf, vh);
    attn_kernel<<<dim3(TT * HH * (WW / SEG), 4), 256, 0, stream>>>(
        qkf, qkf + (size_t)QC, vh, att_bf);
    proj_mfma<<<QTOT / 64, 256, 0, stream>>>(att_bf, wbuf, proj_b, out);
}